// Round 4
// baseline (295.824 us; speedup 1.0000x reference)
//
#include <hip/hip_runtime.h>
#include <hip/hip_bf16.h>
#include <math.h>

#define BATCH 8
#define SEQ   1024
#define DM    768
#define NHEAD 12
#define KVH   4
#define HD    64
#define REP   3

// softmax scale folded into Q weights, exp2 domain: 0.125 * log2(e)
#define QSCALE 0.18033688011112042f

typedef unsigned short u16;
typedef __attribute__((ext_vector_type(8))) __bf16 bf16x8;
typedef __attribute__((ext_vector_type(4))) float f32x4;
typedef __attribute__((ext_vector_type(4))) unsigned int u32x4;
typedef __attribute__((address_space(1))) const unsigned int gu32_c;
typedef __attribute__((address_space(3))) unsigned int su32;

// RTNE fp32 -> bf16 (finite values)
__device__ __forceinline__ u16 f2bf(float f) {
    unsigned int u = __float_as_uint(f);
    u += 0x7fffu + ((u >> 16) & 1u);
    return (u16)(u >> 16);
}

// ======== convert x -> bf16, vectorized (float4 in, ushort4 out) ============
__global__ __launch_bounds__(256) void cvt_x_k(
    const float* __restrict__ in, u16* __restrict__ o, int n4)
{
    const int i = blockIdx.x * 256 + threadIdx.x;
    if (i >= n4) return;
    const float4 v = ((const float4*)in)[i];
    ushort4 r;
    r.x = f2bf(v.x); r.y = f2bf(v.y); r.z = f2bf(v.z); r.w = f2bf(v.w);
    ((ushort4*)o)[i] = r;
}

// ==== build Wt[n][k] bf16 = concat(qw|kw|vw)[k][n] transposed+converted =====
// Q columns pre-scaled by QSCALE (softmax scale folded, exp2 domain).
__global__ __launch_bounds__(256) void cvt_wqkv_k(
    const float* __restrict__ qw, const float* __restrict__ kw,
    const float* __restrict__ vw, u16* __restrict__ wt)
{
    const int idx = blockIdx.x * 256 + threadIdx.x;   // idx = n*768 + k
    if (idx >= 1280 * DM) return;
    const int k = idx % DM;
    const int n = idx / DM;
    float v;
    if (n < 768)       v = qw[(size_t)k * 768 + n] * QSCALE;
    else if (n < 1024) v = kw[(size_t)k * 256 + (n - 768)];
    else               v = vw[(size_t)k * 256 + (n - 1024)];
    wt[idx] = f2bf(v);
}

__global__ __launch_bounds__(256) void cvt_wo_k(
    const float* __restrict__ ow, u16* __restrict__ wt)
{
    const int idx = blockIdx.x * 256 + threadIdx.x;   // idx = n*768 + k
    if (idx >= DM * DM) return;
    const int k = idx % DM;
    const int n = idx / DM;
    wt[idx] = f2bf(ow[(size_t)k * DM + n]);
}

// ======== 128x128-tile bf16 MFMA GEMM body (global_load_lds staging) ========
// A: [M][768] bf16 row-major.  B: [N][768] bf16 row-major (pre-transposed).
// Staging via width-16 global_load_lds: LDS dest is wave-uniform base +
// lane*16 (our chunk layout is linear in lane), global src per-lane.
__device__ __forceinline__ void gemm128_body(
    const u16* __restrict__ A, const u16* __restrict__ B,
    int m0, int n0, u16* As, u16* Bs, f32x4 acc[4][4])
{
    const int tid  = threadIdx.x;
    const int lane = tid & 63;
    const int wid  = tid >> 6;
    const int wr = wid >> 1, wc = wid & 1;
    const int lo = lane & 15, hi = lane >> 4;

    const f32x4 z = {0.f, 0.f, 0.f, 0.f};
    #pragma unroll
    for (int i = 0; i < 4; i++)
        #pragma unroll
        for (int j = 0; j < 4; j++)
            acc[i][j] = z;

    for (int kt = 0; kt < DM; kt += 32) {
        #pragma unroll
        for (int r = 0; r < 2; ++r) {
            const int idx  = r * 256 + tid;           // chunk id, 512 per tile
            const int row  = idx >> 2;
            const int col  = (idx & 3) << 3;
            const int base = (r * 256 + wid * 64) * 8; // wave-uniform LDS elems
            __builtin_amdgcn_global_load_lds(
                (gu32_c*)&A[(size_t)(m0 + row) * DM + kt + col],
                (su32*)&As[base], 16, 0, 0);
            __builtin_amdgcn_global_load_lds(
                (gu32_c*)&B[(size_t)(n0 + row) * DM + kt + col],
                (su32*)&Bs[base], 16, 0, 0);
        }
        __syncthreads();
        bf16x8 af[4], bfr[4];
        #pragma unroll
        for (int i = 0; i < 4; i++) af[i]  = *(const bf16x8*)&As[(wr * 64 + i * 16 + lo) * 32 + hi * 8];
        #pragma unroll
        for (int j = 0; j < 4; j++) bfr[j] = *(const bf16x8*)&Bs[(wc * 64 + j * 16 + lo) * 32 + hi * 8];
        #pragma unroll
        for (int i = 0; i < 4; i++)
            #pragma unroll
            for (int j = 0; j < 4; j++)
                acc[i][j] = __builtin_amdgcn_mfma_f32_16x16x32_bf16(af[i], bfr[j], acc[i][j], 0, 0, 0);
        __syncthreads();
    }
}

// ======== QKV projection -> Q/K head-major [b,h,t,d]; V TRANSPOSED [b,g,d,t]
__global__ __launch_bounds__(256) void gemm_qkv(
    const u16* __restrict__ xb, const u16* __restrict__ wt,
    const float* __restrict__ qb, const float* __restrict__ kb,
    const float* __restrict__ vb,
    u16* __restrict__ Q, u16* __restrict__ K, u16* __restrict__ Vt)
{
    __shared__ __align__(16) u16 As[128 * 32];
    __shared__ __align__(16) u16 Bs[128 * 32];
    // XCD-chunked swizzle (640 % 8 == 0), id m-major so each XCD reuses x-panels
    const int id = (blockIdx.x & 7) * 80 + (blockIdx.x >> 3);
    const int m0 = (id / 10) * 128;
    const int n0 = (id % 10) * 128;
    f32x4 acc[4][4];
    gemm128_body(xb, wt, m0, n0, As, Bs, acc);

    const int tid = threadIdx.x;
    const int lane = tid & 63, wid = tid >> 6;
    const int wr = wid >> 1, wc = wid & 1;
    const int lo = lane & 15, hi = lane >> 4;

    #pragma unroll
    for (int j = 0; j < 4; j++) {
        const int n = n0 + wc * 64 + j * 16 + lo;
        if (n < 1024) {       // Q or K: [b,h,t,d] layout, scalar stores
            u16* outp; int nl, Hcnt; float bias;
            if (n < 768) { outp = Q; nl = n;       Hcnt = NHEAD; bias = qb[n] * QSCALE; }
            else         { outp = K; nl = n - 768; Hcnt = KVH;   bias = kb[nl]; }
            const int head = nl >> 6, d = nl & 63;
            #pragma unroll
            for (int i = 0; i < 4; i++) {
                #pragma unroll
                for (int r = 0; r < 4; r++) {
                    const int m = m0 + wr * 64 + i * 16 + hi * 4 + r;
                    const int b = m >> 10, t = m & 1023;
                    outp[(((size_t)(b * Hcnt + head)) * SEQ + t) * HD + d] =
                        f2bf(acc[i][j][r] + bias);
                }
            }
        } else {              // V: [b,g,d,t] layout, ushort4 stores (4 consecutive t)
            const int nl = n - 1024;
            const float bias = vb[nl];
            const int head = nl >> 6, d = nl & 63;
            #pragma unroll
            for (int i = 0; i < 4; i++) {
                ushort4 vs;
                vs.x = f2bf(acc[i][j][0] + bias);
                vs.y = f2bf(acc[i][j][1] + bias);
                vs.z = f2bf(acc[i][j][2] + bias);
                vs.w = f2bf(acc[i][j][3] + bias);
                const int m = m0 + wr * 64 + i * 16 + hi * 4;
                const int b = m >> 10, t = m & 1023;
                *(ushort4*)&Vt[(((size_t)(b * KVH + head)) * HD + d) * SEQ + t] = vs;
            }
        }
    }
}

// ======== output projection: attn[8192][768] bf16 @ Wo^T + ob -> fp32 =======
__global__ __launch_bounds__(256) void gemm_oproj(
    const u16* __restrict__ Ab, const u16* __restrict__ wt,
    const float* __restrict__ ob, float* __restrict__ outp)
{
    __shared__ __align__(16) u16 As[128 * 32];
    __shared__ __align__(16) u16 Bs[128 * 32];
    const int id = (blockIdx.x & 7) * 48 + (blockIdx.x >> 3);   // 384 % 8 == 0
    const int m0 = (id / 6) * 128;
    const int n0 = (id % 6) * 128;
    f32x4 acc[4][4];
    gemm128_body(Ab, wt, m0, n0, As, Bs, acc);

    const int tid = threadIdx.x;
    const int lane = tid & 63, wid = tid >> 6;
    const int wr = wid >> 1, wc = wid & 1;
    const int lo = lane & 15, hi = lane >> 4;

    #pragma unroll
    for (int j = 0; j < 4; j++) {
        const int n = n0 + wc * 64 + j * 16 + lo;
        const float bias = ob[n];
        #pragma unroll
        for (int i = 0; i < 4; i++) {
            #pragma unroll
            for (int r = 0; r < 4; r++) {
                const int m = m0 + wr * 64 + i * 16 + hi * 4 + r;
                outp[(size_t)m * DM + n] = acc[i][j][r] + bias;
            }
        }
    }
}

// ======== naive RoPE, out-of-place, INTERLEAVED (file-faithful) variant ======
__global__ __launch_bounds__(256) void rope_naive(
    const __hip_bfloat16* __restrict__ in, __hip_bfloat16* __restrict__ outb,
    const int* __restrict__ pos, long long nrows)
{
    const long long gid = (long long)blockIdx.x * 256 + threadIdx.x;
    if (gid >= nrows * 64) return;
    const long long row = gid >> 6;
    const int j = (int)(gid & 63);
    const int t = (int)(row & (SEQ - 1));

    float p;
    if (pos[1] == 1)                              p = (float)pos[t];
    else if (((const float*)pos)[1] == 1.0f)      p = ((const float*)pos)[t];
    else                                          p = (float)pos[2 * t];

    const float inv = exp2f(-(float)(j & 31) * (13.287712379549449f / 32.0f));
    float sv, cv;
    sincosf(p * inv, &sv, &cv);
    const int partner = (j & 1) * 32 + (j >> 1) + ((j < 32) ? 16 : -16);
    const float sign  = (j < 32) ? -1.0f : 1.0f;
    const float val  = __bfloat162float(in[row * HD + j]);
    const float pv   = __bfloat162float(in[row * HD + partner]);
    outb[row * HD + j] = __float2bfloat16(val * cv + sign * pv * sv);
}

// ======== flash attention v4: strip-paired waves, shfl-free softmax =========
// Wave w in [0,32) owns 16-row q-strips sA=63-w (long) and sB=w (short):
// total tiles per wave = 32 or 33 -> uniform work, no tail.
// Scores arrive pre-scaled in log2 domain (QSCALE folded into Q weights):
// p = exp2(sc - m).  Per-lane partial l and per-lane defer-max check keep the
// common path free of cross-lane ops; row reduces deferred to epilogue.
__device__ __forceinline__ void strip_step(
    const f32x4& sv0, const f32x4& sv1, bool diag, int msk0,
    int hi, float& m, float& l, f32x4* O, const bf16x8* vv)
{
    float sc[8];
    #pragma unroll
    for (int e = 0; e < 8; ++e)
        sc[e] = (e < 4) ? sv0[e & 3] : sv1[e & 3];
    if (diag) {
        #pragma unroll
        for (int e = 0; e < 8; ++e) {
            const int srel = ((e >> 2) << 4) + (hi << 2) + (e & 3);
            if (srel > msk0) sc[e] = -3.0e38f;
        }
    }
    float pm = sc[0];
    #pragma unroll
    for (int e = 1; e < 8; ++e) pm = fmaxf(pm, sc[e]);
    if (!__all(pm - m <= 8.0f)) {            // per-lane check == row check
        float pr = fmaxf(pm, __shfl_xor(pm, 16));
        pr = fmaxf(pr, __shfl_xor(pr, 32));
        const float mn = fmaxf(m, pr);
        const float f = exp2f(m - mn);       // first tile: m=-3e38 -> f=0
        l *= f;
        #pragma unroll
        for (int r = 0; r < 4; ++r) {
            const float fr = __shfl(f, hi * 4 + r);
            #pragma unroll
            for (int dj = 0; dj < 4; ++dj) O[dj][r] *= fr;
        }
        m = mn;
    }
    union { unsigned int u[4]; bf16x8 v; } pu;
    float ps = 0.f;
    #pragma unroll
    for (int e2 = 0; e2 < 4; ++e2) {
        const float p0 = exp2f(sc[2 * e2]     - m);
        const float p1 = exp2f(sc[2 * e2 + 1] - m);
        ps += p0 + p1;
        asm("v_cvt_pk_bf16_f32 %0, %1, %2" : "=v"(pu.u[e2]) : "v"(p0), "v"(p1));
    }
    l += ps;                                  // per-lane partial
    __builtin_amdgcn_s_setprio(1);
    #pragma unroll
    for (int dj = 0; dj < 4; ++dj)
        O[dj] = __builtin_amdgcn_mfma_f32_16x16x32_bf16(pu.v, vv[dj], O[dj], 0, 0, 0);
    __builtin_amdgcn_s_setprio(0);
}

__global__ __launch_bounds__(256, 2) void attn_mfma(
    const u16* __restrict__ Q, const u16* __restrict__ K,
    const u16* __restrict__ Vt, u16* __restrict__ outp)
{
    const int wg = (blockIdx.x & 7) * 96 + (blockIdx.x >> 3);   // XCD swizzle
    const int bh = wg >> 3;
    const int c  = wg & 7;
    const int b  = bh / NHEAD, h = bh % NHEAD;
    const int g  = h / REP;
    const int wid  = threadIdx.x >> 6;
    const int lane = threadIdx.x & 63;
    const int lo = lane & 15, hi = lane >> 4;

    const int w  = c + (wid << 3);           // 0..31
    const int sA = 63 - w, sB = w;           // strip pair
    const int nA = (sA >> 1) + 1, nB = (sB >> 1) + 1;
    const int dA = sA >> 1, dB = sB >> 1;
    const int mskA0 = lo + ((sA & 1) << 4);
    const int mskB0 = lo + ((sB & 1) << 4);

    const u16* QpA = Q + ((size_t)(b * NHEAD + h) * SEQ + (sA << 4)) * HD;
    const u16* QpB = Q + ((size_t)(b * NHEAD + h) * SEQ + (sB << 4)) * HD;
    const u16* Kp  = K  + (size_t)(b * KVH + g) * SEQ * HD;
    const u16* Vp  = Vt + (size_t)(b * KVH + g) * SEQ * HD;   // [d][s]

    const bf16x8 qA0 = *(const bf16x8*)&QpA[(size_t)lo * HD + hi * 8];
    const bf16x8 qA1 = *(const bf16x8*)&QpA[(size_t)lo * HD + 32 + hi * 8];
    const bf16x8 qB0 = *(const bf16x8*)&QpB[(size_t)lo * HD + hi * 8];
    const bf16x8 qB1 = *(const bf16x8*)&QpB[(size_t)lo * HD + 32 + hi * 8];

    const f32x4 z = {0.f, 0.f, 0.f, 0.f};
    f32x4 OA[4], OB[4];
    #pragma unroll
    for (int dj = 0; dj < 4; ++dj) { OA[dj] = z; OB[dj] = z; }
    float mA = -3.0e38f, lA = 0.f, mB = -3.0e38f, lB = 0.f;

    bf16x8 k0, k1, k2, k3;
    {
        const u16* kr0 = &Kp[(size_t)lo * HD + hi * 8];
        const u16* kr1 = &Kp[(size_t)(16 + lo) * HD + hi * 8];
        k0 = *(const bf16x8*)&kr0[0];  k1 = *(const bf16x8*)&kr0[32];
        k2 = *(const bf16x8*)&kr1[0];  k3 = *(const bf16x8*)&kr1[32];
    }

    for (int st = 0; st < nA; ++st) {
        const int s0 = st << 5;
        bf16x8 vv[4];
        #pragma unroll
        for (int dj = 0; dj < 4; ++dj) {
            const u16* vr = &Vp[(size_t)(dj * 16 + lo) * SEQ + s0 + hi * 4];
            union { unsigned long long q[2]; bf16x8 v; } vu;
            vu.q[0] = *(const unsigned long long*)&vr[0];
            vu.q[1] = *(const unsigned long long*)&vr[16];
            vv[dj] = vu.v;
        }
        const bool actB = (st < nB);

        f32x4 a0 = z, a1 = z, b0 = z, b1 = z;
        __builtin_amdgcn_s_setprio(1);
        a0 = __builtin_amdgcn_mfma_f32_16x16x32_bf16(k0, qA0, a0, 0, 0, 0);
        a0 = __builtin_amdgcn_mfma_f32_16x16x32_bf16(k1, qA1, a0, 0, 0, 0);
        a1 = __builtin_amdgcn_mfma_f32_16x16x32_bf16(k2, qA0, a1, 0, 0, 0);
        a1 = __builtin_amdgcn_mfma_f32_16x16x32_bf16(k3, qA1, a1, 0, 0, 0);
        if (actB) {
            b0 = __builtin_amdgcn_mfma_f32_16x16x32_bf16(k0, qB0, b0, 0, 0, 0);
            b0 = __builtin_amdgcn_mfma_f32_16x16x32_bf16(k1, qB1, b0, 0, 0, 0);
            b1 = __builtin_amdgcn_mfma_f32_16x16x32_bf16(k2, qB0, b1, 0, 0, 0);
            b1 = __builtin_amdgcn_mfma_f32_16x16x32_bf16(k3, qB1, b1, 0, 0, 0);
        }
        __builtin_amdgcn_s_setprio(0);

        if (st + 1 < nA) {                    // prefetch K, overlaps softmax
            const u16* kr0 = &Kp[(size_t)(s0 + 32 + lo) * HD + hi * 8];
            const u16* kr1 = &Kp[(size_t)(s0 + 48 + lo) * HD + hi * 8];
            k0 = *(const bf16x8*)&kr0[0];  k1 = *(const bf16x8*)&kr0[32];
            k2 = *(const bf16x8*)&kr1[0];  k3 = *(const bf16x8*)&kr1[32];
        }

        strip_step(a0, a1, st == dA, mskA0, hi, mA, lA, OA, vv);
        if (actB) strip_step(b0, b1, st == dB, mskB0, hi, mB, lB, OB, vv);
    }

    // epilogue: reduce per-lane l across hi-groups, then per-row store
    lA += __shfl_xor(lA, 16); lA += __shfl_xor(lA, 32);
    lB += __shfl_xor(lB, 16); lB += __shfl_xor(lB, 32);
    #pragma unroll
    for (int r = 0; r < 4; ++r) {
        const float liA = 1.0f / fmaxf(__shfl(lA, hi * 4 + r), 1e-37f);
        const float liB = 1.0f / fmaxf(__shfl(lB, hi * 4 + r), 1e-37f);
        const int tA = (sA << 4) + hi * 4 + r;
        const int tB = (sB << 4) + hi * 4 + r;
        #pragma unroll
        for (int dj = 0; dj < 4; ++dj) {
            outp[((size_t)(b * SEQ + tA)) * DM + h * HD + dj * 16 + lo] = f2bf(OA[dj][r] * liA);
            outp[((size_t)(b * SEQ + tB)) * DM + h * HD + dj * 16 + lo] = f2bf(OB[dj][r] * liB);
        }
    }
}

extern "C" void kernel_launch(void* const* d_in, const int* in_sizes, int n_in,
                              void* d_out, int out_size, void* d_ws, size_t ws_size,
                              hipStream_t stream) {
    const float* x   = (const float*)d_in[0];
    const int*   pos = (const int*)d_in[1];
    const float* qw  = (const float*)d_in[2];
    const float* qb  = (const float*)d_in[3];
    const float* kw  = (const float*)d_in[4];
    const float* kb  = (const float*)d_in[5];
    const float* vw  = (const float*)d_in[6];
    const float* vb  = (const float*)d_in[7];
    const float* ow  = (const float*)d_in[8];
    const float* ob  = (const float*)d_in[9];
    float* out = (float*)d_out;                 // OUTPUT IS FP32

    u16* xb    = (u16*)d_ws;                                    // 6291456
    u16* Wqkvt = xb    + (size_t)8192 * DM;                     //  983040
    u16* Wot   = Wqkvt + (size_t)1280 * DM;                     //  589824
    u16* Qbuf  = Wot   + (size_t)DM * DM;                       // 6291456
    u16* Kbuf  = Qbuf  + (size_t)BATCH * NHEAD * SEQ * HD;      // 2097152
    u16* Krot  = Kbuf  + (size_t)BATCH * KVH * SEQ * HD;        // 2097152
    u16* Vtb   = Krot  + (size_t)BATCH * KVH * SEQ * HD;        // 2097152 [b,g,d,s]
    u16* Qrot  = xb;     // alias: xb dead after gemm_qkv
    u16* attn  = Qbuf;   // alias: Qbuf dead after rope_q

    cvt_x_k<<<(8192 * DM / 4 + 255) / 256, 256, 0, stream>>>(x, xb, 8192 * DM / 4);
    cvt_wqkv_k<<<(1280 * DM + 255) / 256, 256, 0, stream>>>(qw, kw, vw, Wqkvt);
    cvt_wo_k<<<(DM * DM + 255) / 256, 256, 0, stream>>>(ow, Wot);

    gemm_qkv<<<640, 256, 0, stream>>>(xb, Wqkvt, qb, kb, vb, Qbuf, Kbuf, Vtb);

    const long long qrows = (long long)BATCH * NHEAD * SEQ;   // 98304
    const long long krows = (long long)BATCH * KVH * SEQ;     // 32768
    rope_naive<<<(int)((qrows * 64 + 255) / 256), 256, 0, stream>>>(
        (const __hip_bfloat16*)Qbuf, (__hip_bfloat16*)Qrot, pos, qrows);
    rope_naive<<<(int)((krows * 64 + 255) / 256), 256, 0, stream>>>(
        (const __hip_bfloat16*)Kbuf, (__hip_bfloat16*)Krot, pos, krows);

    attn_mfma<<<96 * 8, 256, 0, stream>>>(Qrot, Krot, Vtb, attn);

    gemm_oproj<<<384, 256, 0, stream>>>(attn, Wot, ob, out);
}